// Round 18
// baseline (1216.928 us; speedup 1.0000x reference)
//
#include <hip/hip_runtime.h>

// Swin window attention, round 18.
// r17 counters: qkv gemm FETCH fixed (60 MB) but dur flat -> not BW-bound;
// WRITE 460 MB vs 231 MB output (32B-segment bf16 stores, 2x amplification);
// MfmaUtil 16% @ 4 blocks/CU (serial stage->drain->compute exposed).
// Changes: (1) gemm 5 blocks/CU (5x32KB = 160KB exactly); (2) bf16 epilogue
// staged through LDS (reuse As/Bs) -> 128B/thread coalesced dwordx4 stores;
// (3) attn V transposed [128][64] XOR-swizzled -> PV B-operand is one
// ds_read_b128 (was 32 scalar u16 reads per head).

#define NTOK 49
#define DIM 384
#define HEADS 12
#define QKV_OC 1152
#define QKV_ELEMS (1152*384)
#define PROJ_ELEMS (384*384)
#define CMB_ELEMS (64*12*49*49)
#define SCALE 0.17677669529663687f

typedef __attribute__((ext_vector_type(8))) __bf16 bf16x8;
typedef __attribute__((ext_vector_type(4))) float f32x4;

union BF8 { bf16x8 v; unsigned short u[8]; uint4 q; };

#define GLOAD_LDS16(gp, lp)                                                  \
  __builtin_amdgcn_global_load_lds(                                          \
      (const __attribute__((address_space(1))) void*)(gp),                   \
      (__attribute__((address_space(3))) void*)(lp), 16, 0, 0)

__device__ __forceinline__ unsigned short f2bf(float f) {
  union { float f; unsigned u; } x; x.f = f;
  unsigned r = x.u + 0x7fffu + ((x.u >> 16) & 1u);   // RNE
  return (unsigned short)(r >> 16);
}

__device__ __forceinline__ bf16x8 zbf8() {
  BF8 z;
  #pragma unroll
  for (int j = 0; j < 8; ++j) z.u[j] = 0;
  return z.v;
}

// ---- prep: weights -> bf16 pre-swizzled image (scale folded), cmb, bias ----
__global__ void prep_kernel(const float* __restrict__ qkv_w,
                            const float* __restrict__ proj_w,
                            const float* __restrict__ bias_table,
                            const int* __restrict__ rel_idx,
                            const float* __restrict__ mask,
                            const float* __restrict__ qkv_b,
                            unsigned short* __restrict__ wq,
                            unsigned short* __restrict__ wp,
                            float* __restrict__ cmb,
                            float* __restrict__ qb2) {
  int i = blockIdx.x * 256 + threadIdx.x;
  if (i < QKV_ELEMS) {
    int c = i / 384, j = i % 384, s = j >> 3, e = j & 7;
    float v = qkv_w[c * 384 + ((s ^ (c & 7)) << 3) + e];
    if (c < 384) v *= SCALE;
    wq[i] = f2bf(v);
  } else if (i < QKV_ELEMS + PROJ_ELEMS) {
    int k = i - QKV_ELEMS;
    int c = k / 384, j = k % 384, s = j >> 3, e = j & 7;
    wp[k] = f2bf(proj_w[c * 384 + ((s ^ (c & 7)) << 3) + e]);
  } else if (i < QKV_ELEMS + PROJ_ELEMS + CMB_ELEMS) {
    int j = i - QKV_ELEMS - PROJ_ELEMS;
    int row = j % 49;
    int tok = (j / 49) % 49;
    int h   = (j / 2401) % 12;
    int wi  = j / (2401 * 12);
    cmb[j] = bias_table[rel_idx[row * 49 + tok] * HEADS + h]
           + mask[(wi * 49 + row) * 49 + tok];
  } else if (i < QKV_ELEMS + PROJ_ELEMS + CMB_ELEMS + QKV_OC) {
    int c = i - QKV_ELEMS - PROJ_ELEMS - CMB_ELEMS;
    qb2[c] = qkv_b[c] * (c < 384 ? SCALE : 1.0f);
  }
}

// ---- convx: x fp32 -> bf16 swizzled image ----
__global__ void convx_kernel(const float* __restrict__ x,
                             unsigned short* __restrict__ xsw, long ngran) {
  long gidx = (long)blockIdx.x * 256 + threadIdx.x;
  if (gidx >= ngran) return;
  int r = (int)(gidx / 48), s = (int)(gidx % 48);
  int ssrc = (s & 56) | ((s & 7) ^ (r & 7));
  const float* src = x + (size_t)r * 384 + ssrc * 8;
  float4 f0 = *(const float4*)src;
  float4 f1 = *(const float4*)(src + 4);
  BF8 t;
  t.u[0] = f2bf(f0.x); t.u[1] = f2bf(f0.y); t.u[2] = f2bf(f0.z); t.u[3] = f2bf(f0.w);
  t.u[4] = f2bf(f1.x); t.u[5] = f2bf(f1.y); t.u[6] = f2bf(f1.z); t.u[7] = f2bf(f1.w);
  *(uint4*)(xsw + (size_t)r * 384 + s * 8) = t.q;
}

// ---- gemm128: 128x128 tile, BK=64, 4 waves (2x2), acc 4x4 ----------------
// Pre-swizzled images -> linear staging; LDS read XOR undoes swizzle.
// XCD-chunked + colp-fastest block order. 5 blocks/CU. bf16 epilogue via LDS.
template<int BF16OUT>
__global__ __launch_bounds__(256, 5) void gemm128(
    const unsigned short* __restrict__ Asw, const unsigned short* __restrict__ Wsw,
    const float* __restrict__ bias, void* __restrict__ Cout,
    int Mrows, int Ntot, int ncp) {
  __shared__ alignas(16) unsigned short Buf[16384];     // 32 KB: As | Bs
  unsigned short* As = Buf;
  unsigned short* Bs = Buf + 8192;
  const int nwg = gridDim.x;
  const int bid = blockIdx.x;
  const int q8 = nwg >> 3, r8 = nwg & 7;
  const int xcd = bid & 7, lin = bid >> 3;
  const int wgid = (xcd < r8 ? xcd * (q8 + 1) : r8 * (q8 + 1) + (xcd - r8) * q8) + lin;
  const int colp = wgid % ncp, rowb = wgid / ncp;   // colp fastest: A reuse
  const int tb = rowb * 128, nb = colp * 128;
  const int tid = threadIdx.x;
  const int wave = tid >> 6, lane = tid & 63, g = lane >> 4, li = lane & 15;
  const int wr = wave >> 1, wc = wave & 1;
  const int chbase = wave * 256 + lane;

  f32x4 acc[4][4];
  #pragma unroll
  for (int m = 0; m < 4; ++m)
    #pragma unroll
    for (int n = 0; n < 4; ++n) acc[m][n] = (f32x4){0.f, 0.f, 0.f, 0.f};

  #pragma unroll 1
  for (int step = 0; step < 6; ++step) {
    const int k0 = step * 64;
    if (step) __syncthreads();
    #pragma unroll
    for (int i = 0; i < 4; ++i) {
      int ch = chbase + i * 64;
      int r = ch >> 3, s = ch & 7;
      GLOAD_LDS16(Asw + (size_t)(tb + r) * 384 + k0 + s * 8, As + ch * 8);
    }
    #pragma unroll
    for (int i = 0; i < 4; ++i) {
      int ch = chbase + i * 64;
      int c = ch >> 3, s = ch & 7;
      GLOAD_LDS16(Wsw + (size_t)(nb + c) * 384 + k0 + s * 8, Bs + ch * 8);
    }
    __syncthreads();

    #pragma unroll
    for (int kk = 0; kk < 2; ++kk) {
      const int goff = ((kk * 4 + g) ^ (li & 7)) << 3;
      bf16x8 a0 = *(const bf16x8*)&As[(wr * 64 +  0 + li) * 64 + goff];
      bf16x8 a1 = *(const bf16x8*)&As[(wr * 64 + 16 + li) * 64 + goff];
      bf16x8 a2 = *(const bf16x8*)&As[(wr * 64 + 32 + li) * 64 + goff];
      bf16x8 a3 = *(const bf16x8*)&As[(wr * 64 + 48 + li) * 64 + goff];
      bf16x8 b0 = *(const bf16x8*)&Bs[(wc * 64 +  0 + li) * 64 + goff];
      bf16x8 b1 = *(const bf16x8*)&Bs[(wc * 64 + 16 + li) * 64 + goff];
      bf16x8 b2 = *(const bf16x8*)&Bs[(wc * 64 + 32 + li) * 64 + goff];
      bf16x8 b3 = *(const bf16x8*)&Bs[(wc * 64 + 48 + li) * 64 + goff];
      acc[0][0] = __builtin_amdgcn_mfma_f32_16x16x32_bf16(a0, b0, acc[0][0], 0, 0, 0);
      acc[0][1] = __builtin_amdgcn_mfma_f32_16x16x32_bf16(a0, b1, acc[0][1], 0, 0, 0);
      acc[0][2] = __builtin_amdgcn_mfma_f32_16x16x32_bf16(a0, b2, acc[0][2], 0, 0, 0);
      acc[0][3] = __builtin_amdgcn_mfma_f32_16x16x32_bf16(a0, b3, acc[0][3], 0, 0, 0);
      acc[1][0] = __builtin_amdgcn_mfma_f32_16x16x32_bf16(a1, b0, acc[1][0], 0, 0, 0);
      acc[1][1] = __builtin_amdgcn_mfma_f32_16x16x32_bf16(a1, b1, acc[1][1], 0, 0, 0);
      acc[1][2] = __builtin_amdgcn_mfma_f32_16x16x32_bf16(a1, b2, acc[1][2], 0, 0, 0);
      acc[1][3] = __builtin_amdgcn_mfma_f32_16x16x32_bf16(a1, b3, acc[1][3], 0, 0, 0);
      acc[2][0] = __builtin_amdgcn_mfma_f32_16x16x32_bf16(a2, b0, acc[2][0], 0, 0, 0);
      acc[2][1] = __builtin_amdgcn_mfma_f32_16x16x32_bf16(a2, b1, acc[2][1], 0, 0, 0);
      acc[2][2] = __builtin_amdgcn_mfma_f32_16x16x32_bf16(a2, b2, acc[2][2], 0, 0, 0);
      acc[2][3] = __builtin_amdgcn_mfma_f32_16x16x32_bf16(a2, b3, acc[2][3], 0, 0, 0);
      acc[3][0] = __builtin_amdgcn_mfma_f32_16x16x32_bf16(a3, b0, acc[3][0], 0, 0, 0);
      acc[3][1] = __builtin_amdgcn_mfma_f32_16x16x32_bf16(a3, b1, acc[3][1], 0, 0, 0);
      acc[3][2] = __builtin_amdgcn_mfma_f32_16x16x32_bf16(a3, b2, acc[3][2], 0, 0, 0);
      acc[3][3] = __builtin_amdgcn_mfma_f32_16x16x32_bf16(a3, b3, acc[3][3], 0, 0, 0);
    }
  }

  if (BF16OUT) {
    // epilogue via LDS: acc -> swizzled [128][128] bf16 tile -> coalesced
    // 128B/thread dwordx4 global stores (kills 32B-segment write amplification)
    __syncthreads();   // all waves done reading As/Bs
    #pragma unroll
    for (int n = 0; n < 4; ++n) {
      int colL = wc * 64 + n * 16 + li;
      float bv = bias[nb + colL];
      int gg = colL >> 3, ge = colL & 7;
      #pragma unroll
      for (int m = 0; m < 4; ++m) {
        #pragma unroll
        for (int r4 = 0; r4 < 4; ++r4) {
          int row = wr * 64 + m * 16 + g * 4 + r4;
          Buf[row * 128 + ((gg ^ (row & 7)) << 3) + ge] = f2bf(acc[m][n][r4] + bv);
        }
      }
    }
    __syncthreads();
    const int row = tid >> 1, half = tid & 1;
    if (tb + row < Mrows) {
      unsigned short* dst = (unsigned short*)Cout + (size_t)(tb + row) * Ntot + nb + half * 64;
      #pragma unroll
      for (int i = 0; i < 8; ++i) {
        int gg = half * 8 + i;
        *(uint4*)(dst + i * 8) = *(const uint4*)&Buf[row * 128 + ((gg ^ (row & 7)) << 3)];
      }
    }
  } else {
    // f32 out: 16 lanes x 4B = full 64B lines, no amplification
    #pragma unroll
    for (int n = 0; n < 4; ++n) {
      int col = nb + wc * 64 + n * 16 + li;
      float bv = bias[col];
      #pragma unroll
      for (int m = 0; m < 4; ++m) {
        #pragma unroll
        for (int r4 = 0; r4 < 4; ++r4) {
          int row = tb + wr * 64 + m * 16 + g * 4 + r4;
          if (row < Mrows)
            ((float*)Cout)[(size_t)row * Ntot + col] = acc[m][n][r4] + bv;
        }
      }
    }
  }
}

// ---- attn: q direct from qkv; K swizzled + V transposed-swizzled in LDS ---
#define AT_K 0                     // [49][128] swizzled K chunk (12.25 KB)
#define AT_VT (49*128)             // [128 ch][64 tok] swizzled vT (16 KB)
#define AT_ELEMS (AT_VT + 128*64)  // 14464 elems = 28928 B

__global__ __launch_bounds__(512, 8) void attn_kernel(
    const unsigned short* __restrict__ qkv,   // [WB*49][1152] linear
    const float* __restrict__ cmb,
    unsigned short* __restrict__ Obuf,        // [WB*49][384] swizzled image
    int wb0) {
  __shared__ unsigned short lds[AT_ELEMS];
  const int tid  = threadIdx.x;
  const int wave = tid >> 6, lane = tid & 63;
  const int g = lane >> 4, li = lane & 15;
  const int relw = blockIdx.x;
  const int wi = (wb0 + relw) & 63;
  const size_t rowbase = (size_t)relw * 49;
  const int mgrp = wave >> 1, ng = wave & 1;
  const int arow = mgrp * 16 + li;

  // zero vT once (pad toks 49..63 stay zero; staging writes only tok<49)
  {
    uint4 z4 = {0u, 0u, 0u, 0u};
    uint4* p = (uint4*)(lds + AT_VT);
    p[tid] = z4;
    p[tid + 512] = z4;
  }

  #pragma unroll 1
  for (int c = 0; c < 3; ++c) {
    if (c) __syncthreads();
    // stage K chunk [49][128] swizzled
    #pragma unroll
    for (int it = 0; it < 2; ++it) {
      int gidx = it * 512 + tid;
      if (gidx < 784) {
        int row = gidx >> 4, gc = gidx & 15;
        bf16x8 v = *(const bf16x8*)(qkv + (rowbase + row) * 1152 + 384 + c * 128 + gc * 8);
        *(bf16x8*)&lds[AT_K + row * 128 + ((gc ^ (row & 7)) << 3)] = v;
      }
    }
    // stage V chunk transposed: vT[ch][tok ^ ((ch&7)<<3)] (element-level key)
    #pragma unroll
    for (int it = 0; it < 2; ++it) {
      int gidx = it * 512 + tid;
      if (gidx < 784) {
        int row = gidx >> 4, gc = gidx & 15;   // row = tok, gc*8.. = channels
        BF8 v;
        v.q = *(const uint4*)(qkv + (rowbase + row) * 1152 + 768 + c * 128 + gc * 8);
        #pragma unroll
        for (int e = 0; e < 8; ++e) {
          int ch = gc * 8 + e;                 // ch & 7 == e
          lds[AT_VT + ch * 64 + (row ^ (e << 3))] = v.u[e];
        }
      }
    }
    __syncthreads();

    #pragma unroll 1
    for (int b = 0; b < 2; ++b) {
      const int hh = ng * 2 + b;
      const int h  = c * 4 + hh;

      bf16x8 qa = (arow < NTOK)
          ? *(const bf16x8*)(qkv + (rowbase + arow) * 1152 + h * 32 + g * 8)
          : zbf8();

      f32x4 sv[4];
      #pragma unroll
      for (int nt = 0; nt < 4; ++nt) {
        int tok = nt * 16 + li;
        bf16x8 kf = (tok < NTOK)
            ? *(const bf16x8*)&lds[AT_K + tok * 128 + (((hh * 4 + g) ^ (tok & 7)) << 3)]
            : zbf8();
        f32x4 z4 = (f32x4){0.f, 0.f, 0.f, 0.f};
        sv[nt] = __builtin_amdgcn_mfma_f32_16x16x32_bf16(kf, qa, z4, 0, 0, 0);
      }

      const float* cb = cmb + (size_t)(wi * HEADS + h) * (NTOK * NTOK);
      #pragma unroll
      for (int nt = 0; nt < 4; ++nt) {
        #pragma unroll
        for (int r4 = 0; r4 < 4; ++r4) {
          int tok = nt * 16 + g * 4 + r4;
          float v;
          if (tok < NTOK) {
            v = sv[nt][r4];
            if (arow < NTOK) v += cb[tok * NTOK + arow];
          } else {
            v = -1e30f;
          }
          sv[nt][r4] = v;
        }
      }

      float m = -1e30f;
      #pragma unroll
      for (int nt = 0; nt < 4; ++nt)
        #pragma unroll
        for (int r4 = 0; r4 < 4; ++r4) m = fmaxf(m, sv[nt][r4]);
      m = fmaxf(m, __shfl_xor(m, 16));
      m = fmaxf(m, __shfl_xor(m, 32));
      float s = 0.f;
      #pragma unroll
      for (int nt = 0; nt < 4; ++nt)
        #pragma unroll
        for (int r4 = 0; r4 < 4; ++r4) {
          float e = __expf(sv[nt][r4] - m);
          sv[nt][r4] = e;
          s += e;
        }
      s += __shfl_xor(s, 16);
      s += __shfl_xor(s, 32);
      float inv = 1.f / s;
      #pragma unroll
      for (int nt = 0; nt < 4; ++nt)
        #pragma unroll
        for (int r4 = 0; r4 < 4; ++r4) sv[nt][r4] *= inv;

      bf16x8 pa[2];
      #pragma unroll
      for (int k2 = 0; k2 < 2; ++k2) {
        BF8 pf;
        #pragma unroll
        for (int j = 0; j < 8; ++j) {
          int srcLane = (((g * 2 + (j >> 2)) & 3) << 4) | li;
          float v0 = __shfl(sv[k2 * 2][j & 3], srcLane);
          float v1 = __shfl(sv[k2 * 2 + 1][j & 3], srcLane);
          pf.u[j] = f2bf((g >= 2) ? v1 : v0);
        }
        pa[k2] = pf.v;
      }

      f32x4 oa[2];
      oa[0] = (f32x4){0.f, 0.f, 0.f, 0.f};
      oa[1] = (f32x4){0.f, 0.f, 0.f, 0.f};
      #pragma unroll
      for (int k2 = 0; k2 < 2; ++k2) {
        #pragma unroll
        for (int nt2 = 0; nt2 < 2; ++nt2) {
          int ch = hh * 32 + nt2 * 16 + li;
          int tg = k2 * 4 + g;                 // tok granule
          bf16x8 vb = *(const bf16x8*)&lds[AT_VT + ch * 64 + ((tg ^ (ch & 7)) << 3)];
          oa[nt2] = __builtin_amdgcn_mfma_f32_16x16x32_bf16(pa[k2], vb, oa[nt2], 0, 0, 0);
        }
      }

      // O -> swizzled image, keyed to the GLOBAL row
      #pragma unroll
      for (int nt2 = 0; nt2 < 2; ++nt2) {
        int colb = h * 32 + nt2 * 16 + li;
        int gran = colb >> 3;
        #pragma unroll
        for (int r4 = 0; r4 < 4; ++r4) {
          int row = mgrp * 16 + g * 4 + r4;
          if (row < NTOK) {
            int grow = (int)(rowbase) + row;
            int col2 = (((gran & 56) | ((gran & 7) ^ (grow & 7))) << 3) | (colb & 7);
            Obuf[(size_t)grow * 384 + col2] = f2bf(oa[nt2][r4]);
          }
        }
      }
    }
  }
}

extern "C" void kernel_launch(void* const* d_in, const int* in_sizes, int n_in,
                              void* d_out, int out_size, void* d_ws, size_t ws_size,
                              hipStream_t stream) {
  (void)in_sizes; (void)n_in; (void)out_size;
  const float* x          = (const float*)d_in[0];
  const float* mask       = (const float*)d_in[1];
  const float* qkv_w      = (const float*)d_in[2];
  const float* qkv_b      = (const float*)d_in[3];
  const float* proj_w     = (const float*)d_in[4];
  const float* proj_b     = (const float*)d_in[5];
  const float* bias_table = (const float*)d_in[6];
  const int*   rel_idx    = (const int*)d_in[7];
  float* out = (float*)d_out;

  char* ws = (char*)d_ws;
  size_t off = 0;
  unsigned short* wq  = (unsigned short*)(ws + off); off += (size_t)QKV_ELEMS * 2;
  unsigned short* wp  = (unsigned short*)(ws + off); off += (size_t)PROJ_ELEMS * 2;
  float*          qb2 = (float*)(ws + off);          off += (size_t)QKV_OC * 4;
  float*          cmb = (float*)(ws + off);          off += (size_t)CMB_ELEMS * 4;
  const size_t fixed = off;

  const int cands[7] = {2048, 4096, 1024, 512, 256, 128, 64};
  int WB = 64;
  for (int ci = 0; ci < 7; ++ci) {
    int mrows = cands[ci] * 49;
    int mpad = ((mrows + 127) / 128) * 128;
    size_t need = fixed + (size_t)mpad * 384 * 2 + (size_t)mrows * 1152 * 2;
    if (need <= ws_size) { WB = cands[ci]; break; }
  }
  const int Mrows = WB * 49;
  const int Mpad  = ((Mrows + 127) / 128) * 128;
  const int NRB   = Mpad / 128;
  unsigned short* xsw = (unsigned short*)(ws + fixed);   // x image / O image
  unsigned short* qkv = xsw + (size_t)Mpad * 384;

  const int prep_total = QKV_ELEMS + PROJ_ELEMS + CMB_ELEMS + QKV_OC;
  prep_kernel<<<(prep_total + 255) / 256, 256, 0, stream>>>(
      qkv_w, proj_w, bias_table, rel_idx, mask, qkv_b, wq, wp, cmb, qb2);

  const int NB = 4096 / WB;
  const long ngran = (long)Mrows * 48;
  for (int b = 0; b < NB; ++b) {
    convx_kernel<<<(int)((ngran + 255) / 256), 256, 0, stream>>>(
        x + (size_t)b * Mrows * 384, xsw, ngran);
    gemm128<1><<<NRB * 9, 256, 0, stream>>>(xsw, wq, qb2, (void*)qkv,
                                            Mrows, 1152, 9);
    attn_kernel<<<WB, 512, 0, stream>>>(qkv, cmb, xsw, b * WB);
    gemm128<0><<<NRB * 3, 256, 0, stream>>>(xsw, wp, proj_b,
        (void*)(out + (size_t)b * Mrows * 384), Mrows, 384, 3);
  }
}

// Round 19
// 1073.379 us; speedup vs baseline: 1.1337x; 1.1337x over previous
//
#include <hip/hip_runtime.h>

// Swin window attention, round 19.
// r18 regressed (LDS epilogue + attn-vT) -> reverted to r17 forms.
// r17 residual: gemm stage->drain->compute->barrier exposes full L2 latency
// per K-step (machine 83% idle, MfmaUtil 16%). Fix: minimum-2-phase prefetch
// (T3): per step {stage buf^1 for t+1; compute buf for t; barrier} -- load
// latency hides under compute. BK 64->32 so double-buffer stays 32 KB
// (4 blocks/CU preserved). Image swizzle key (c>>1)&3 (row-pair key keeps
// b128 reads bank-conflict-free at 64B row stride); propagated to prep,
// convx, attn O-writeback. WB=4096 preferred when ws allows.

#define NTOK 49
#define DIM 384
#define HEADS 12
#define QKV_OC 1152
#define QKV_ELEMS (1152*384)
#define PROJ_ELEMS (384*384)
#define CMB_ELEMS (64*12*49*49)
#define SCALE 0.17677669529663687f

typedef __attribute__((ext_vector_type(8))) __bf16 bf16x8;
typedef __attribute__((ext_vector_type(4))) float f32x4;

union BF8 { bf16x8 v; unsigned short u[8]; uint4 q; };

#define GLOAD_LDS16(gp, lp)                                                  \
  __builtin_amdgcn_global_load_lds(                                          \
      (const __attribute__((address_space(1))) void*)(gp),                   \
      (__attribute__((address_space(3))) void*)(lp), 16, 0, 0)

__device__ __forceinline__ unsigned short f2bf(float f) {
  union { float f; unsigned u; } x; x.f = f;
  unsigned r = x.u + 0x7fffu + ((x.u >> 16) & 1u);   // RNE
  return (unsigned short)(r >> 16);
}

__device__ __forceinline__ bf16x8 zbf8() {
  BF8 z;
  #pragma unroll
  for (int j = 0; j < 8; ++j) z.u[j] = 0;
  return z.v;
}

// image[c][s*8+e] = W[c][swz4(s,c)*8+e], key = (c>>1)&3 within 4-granule window
__device__ __forceinline__ int swz4(int s, int c) {
  return (s & ~3) | ((s & 3) ^ ((c >> 1) & 3));
}

// ---- prep: weights -> bf16 pre-swizzled image (scale folded), cmb, bias ----
__global__ void prep_kernel(const float* __restrict__ qkv_w,
                            const float* __restrict__ proj_w,
                            const float* __restrict__ bias_table,
                            const int* __restrict__ rel_idx,
                            const float* __restrict__ mask,
                            const float* __restrict__ qkv_b,
                            unsigned short* __restrict__ wq,
                            unsigned short* __restrict__ wp,
                            float* __restrict__ cmb,
                            float* __restrict__ qb2) {
  int i = blockIdx.x * 256 + threadIdx.x;
  if (i < QKV_ELEMS) {
    int c = i / 384, j = i % 384, s = j >> 3, e = j & 7;
    float v = qkv_w[c * 384 + swz4(s, c) * 8 + e];
    if (c < 384) v *= SCALE;
    wq[i] = f2bf(v);
  } else if (i < QKV_ELEMS + PROJ_ELEMS) {
    int k = i - QKV_ELEMS;
    int c = k / 384, j = k % 384, s = j >> 3, e = j & 7;
    wp[k] = f2bf(proj_w[c * 384 + swz4(s, c) * 8 + e]);
  } else if (i < QKV_ELEMS + PROJ_ELEMS + CMB_ELEMS) {
    int j = i - QKV_ELEMS - PROJ_ELEMS;
    int row = j % 49;
    int tok = (j / 49) % 49;
    int h   = (j / 2401) % 12;
    int wi  = j / (2401 * 12);
    cmb[j] = bias_table[rel_idx[row * 49 + tok] * HEADS + h]
           + mask[(wi * 49 + row) * 49 + tok];
  } else if (i < QKV_ELEMS + PROJ_ELEMS + CMB_ELEMS + QKV_OC) {
    int c = i - QKV_ELEMS - PROJ_ELEMS - CMB_ELEMS;
    qb2[c] = qkv_b[c] * (c < 384 ? SCALE : 1.0f);
  }
}

// ---- convx: x fp32 -> bf16 swizzled image ----
__global__ void convx_kernel(const float* __restrict__ x,
                             unsigned short* __restrict__ xsw, long ngran) {
  long gidx = (long)blockIdx.x * 256 + threadIdx.x;
  if (gidx >= ngran) return;
  int r = (int)(gidx / 48), s = (int)(gidx % 48);
  const float* src = x + (size_t)r * 384 + swz4(s, r) * 8;
  float4 f0 = *(const float4*)src;
  float4 f1 = *(const float4*)(src + 4);
  BF8 t;
  t.u[0] = f2bf(f0.x); t.u[1] = f2bf(f0.y); t.u[2] = f2bf(f0.z); t.u[3] = f2bf(f0.w);
  t.u[4] = f2bf(f1.x); t.u[5] = f2bf(f1.y); t.u[6] = f2bf(f1.z); t.u[7] = f2bf(f1.w);
  *(uint4*)(xsw + (size_t)r * 384 + s * 8) = t.q;
}

// ---- gemm128: 128x128 tile, BK=32 double-buffered prefetch pipeline -------
// 12 K-steps: {stage(buf^1, t+1) async; compute(buf, t): 8 ds_read_b128 +
// 16 MFMA; barrier}. LDS 32 KB -> 4 blocks/CU. XCD-chunked + colp-fastest.
template<int BF16OUT>
__global__ __launch_bounds__(256, 4) void gemm128(
    const unsigned short* __restrict__ Asw, const unsigned short* __restrict__ Wsw,
    const float* __restrict__ bias, void* __restrict__ Cout,
    int Mrows, int Ntot, int ncp) {
  __shared__ alignas(16) unsigned short As[2][128 * 32];   // 2 x 8 KB
  __shared__ alignas(16) unsigned short Bs[2][128 * 32];   // 2 x 8 KB
  const int nwg = gridDim.x;
  const int bid = blockIdx.x;
  const int q8 = nwg >> 3, r8 = nwg & 7;
  const int xcd = bid & 7, lin = bid >> 3;
  const int wgid = (xcd < r8 ? xcd * (q8 + 1) : r8 * (q8 + 1) + (xcd - r8) * q8) + lin;
  const int colp = wgid % ncp, rowb = wgid / ncp;   // colp fastest: A reuse
  const int tb = rowb * 128, nb = colp * 128;
  const int tid = threadIdx.x;
  const int wave = tid >> 6, lane = tid & 63, g = lane >> 4, li = lane & 15;
  const int wr = wave >> 1, wc = wave & 1;
  const int chbase = wave * 128 + lane;   // 2 chunks/thread per tile

  f32x4 acc[4][4];
  #pragma unroll
  for (int m = 0; m < 4; ++m)
    #pragma unroll
    for (int n = 0; n < 4; ++n) acc[m][n] = (f32x4){0.f, 0.f, 0.f, 0.f};

  // stage tile `st` (granule window st*4) into buffer `bu`
  auto stage = [&](int bu, int st) {
    const int k0 = st * 32;
    #pragma unroll
    for (int i = 0; i < 2; ++i) {
      int ch = chbase + i * 64;            // 0..511
      int r = ch >> 2, s = ch & 3;
      GLOAD_LDS16(Asw + (size_t)(tb + r) * 384 + k0 + s * 8,
                  (unsigned short*)As[bu] + ch * 8);
    }
    #pragma unroll
    for (int i = 0; i < 2; ++i) {
      int ch = chbase + i * 64;
      int c = ch >> 2, s = ch & 3;
      GLOAD_LDS16(Wsw + (size_t)(nb + c) * 384 + k0 + s * 8,
                  (unsigned short*)Bs[bu] + ch * 8);
    }
  };

  stage(0, 0);
  __syncthreads();   // drain -> tile 0 resident

  #pragma unroll 1
  for (int st = 0; st < 12; ++st) {
    const int cur = st & 1;
    if (st + 1 < 12) stage(cur ^ 1, st + 1);   // prefetch before compute

    const int goff = ((g ^ ((li >> 1) & 3)) << 3);
    bf16x8 a0 = *(const bf16x8*)&As[cur][(wr * 64 +  0 + li) * 32 + goff];
    bf16x8 a1 = *(const bf16x8*)&As[cur][(wr * 64 + 16 + li) * 32 + goff];
    bf16x8 a2 = *(const bf16x8*)&As[cur][(wr * 64 + 32 + li) * 32 + goff];
    bf16x8 a3 = *(const bf16x8*)&As[cur][(wr * 64 + 48 + li) * 32 + goff];
    bf16x8 b0 = *(const bf16x8*)&Bs[cur][(wc * 64 +  0 + li) * 32 + goff];
    bf16x8 b1 = *(const bf16x8*)&Bs[cur][(wc * 64 + 16 + li) * 32 + goff];
    bf16x8 b2 = *(const bf16x8*)&Bs[cur][(wc * 64 + 32 + li) * 32 + goff];
    bf16x8 b3 = *(const bf16x8*)&Bs[cur][(wc * 64 + 48 + li) * 32 + goff];
    acc[0][0] = __builtin_amdgcn_mfma_f32_16x16x32_bf16(a0, b0, acc[0][0], 0, 0, 0);
    acc[0][1] = __builtin_amdgcn_mfma_f32_16x16x32_bf16(a0, b1, acc[0][1], 0, 0, 0);
    acc[0][2] = __builtin_amdgcn_mfma_f32_16x16x32_bf16(a0, b2, acc[0][2], 0, 0, 0);
    acc[0][3] = __builtin_amdgcn_mfma_f32_16x16x32_bf16(a0, b3, acc[0][3], 0, 0, 0);
    acc[1][0] = __builtin_amdgcn_mfma_f32_16x16x32_bf16(a1, b0, acc[1][0], 0, 0, 0);
    acc[1][1] = __builtin_amdgcn_mfma_f32_16x16x32_bf16(a1, b1, acc[1][1], 0, 0, 0);
    acc[1][2] = __builtin_amdgcn_mfma_f32_16x16x32_bf16(a1, b2, acc[1][2], 0, 0, 0);
    acc[1][3] = __builtin_amdgcn_mfma_f32_16x16x32_bf16(a1, b3, acc[1][3], 0, 0, 0);
    acc[2][0] = __builtin_amdgcn_mfma_f32_16x16x32_bf16(a2, b0, acc[2][0], 0, 0, 0);
    acc[2][1] = __builtin_amdgcn_mfma_f32_16x16x32_bf16(a2, b1, acc[2][1], 0, 0, 0);
    acc[2][2] = __builtin_amdgcn_mfma_f32_16x16x32_bf16(a2, b2, acc[2][2], 0, 0, 0);
    acc[2][3] = __builtin_amdgcn_mfma_f32_16x16x32_bf16(a2, b3, acc[2][3], 0, 0, 0);
    acc[3][0] = __builtin_amdgcn_mfma_f32_16x16x32_bf16(a3, b0, acc[3][0], 0, 0, 0);
    acc[3][1] = __builtin_amdgcn_mfma_f32_16x16x32_bf16(a3, b1, acc[3][1], 0, 0, 0);
    acc[3][2] = __builtin_amdgcn_mfma_f32_16x16x32_bf16(a3, b2, acc[3][2], 0, 0, 0);
    acc[3][3] = __builtin_amdgcn_mfma_f32_16x16x32_bf16(a3, b3, acc[3][3], 0, 0, 0);

    __syncthreads();   // drains prefetch; guards buffer reuse
  }

  // epilogue (r17 direct stores)
  #pragma unroll
  for (int n = 0; n < 4; ++n) {
    int col = nb + wc * 64 + n * 16 + li;
    float bv = bias[col];
    #pragma unroll
    for (int m = 0; m < 4; ++m) {
      #pragma unroll
      for (int r4 = 0; r4 < 4; ++r4) {
        int row = tb + wr * 64 + m * 16 + g * 4 + r4;
        if (row < Mrows) {
          float v = acc[m][n][r4] + bv;
          if (BF16OUT) ((unsigned short*)Cout)[(size_t)row * Ntot + col] = f2bf(v);
          else         ((float*)Cout)[(size_t)row * Ntot + col] = v;
        }
      }
    }
  }
}

// ---- attn (r17): q direct from qkv; K swizzled + V row-major in LDS -------
#define AT_K 0                   // [49][128] swizzled K chunk
#define AT_V (49*128)            // [49][138] plain V chunk (bank-spread)
#define AT_ELEMS (AT_V + 49*138)

__global__ __launch_bounds__(512, 6) void attn_kernel(
    const unsigned short* __restrict__ qkv,   // [WB*49][1152] linear
    const float* __restrict__ cmb,
    unsigned short* __restrict__ Obuf,        // [WB*49][384] swizzled image
    int wb0) {
  __shared__ unsigned short lds[AT_ELEMS];
  const int tid  = threadIdx.x;
  const int wave = tid >> 6, lane = tid & 63;
  const int g = lane >> 4, li = lane & 15;
  const int relw = blockIdx.x;
  const int wi = (wb0 + relw) & 63;
  const size_t rowbase = (size_t)relw * 49;
  const int mgrp = wave >> 1, ng = wave & 1;
  const int arow = mgrp * 16 + li;

  #pragma unroll 1
  for (int c = 0; c < 3; ++c) {
    if (c) __syncthreads();
    #pragma unroll
    for (int it = 0; it < 2; ++it) {
      int gidx = it * 512 + tid;
      if (gidx < 784) {
        int row = gidx >> 4, gc = gidx & 15;
        bf16x8 v = *(const bf16x8*)(qkv + (rowbase + row) * 1152 + 384 + c * 128 + gc * 8);
        *(bf16x8*)&lds[AT_K + row * 128 + ((gc ^ (row & 7)) << 3)] = v;
      }
    }
    #pragma unroll
    for (int it = 0; it < 2; ++it) {
      int gidx = it * 512 + tid;
      if (gidx < 784) {
        int row = gidx >> 4, gc = gidx & 15;
        BF8 v;
        v.q = *(const uint4*)(qkv + (rowbase + row) * 1152 + 768 + c * 128 + gc * 8);
        int e = AT_V + row * 138 + gc * 8;
        *(unsigned*)&lds[e]     = v.q.x;
        *(unsigned*)&lds[e + 2] = v.q.y;
        *(unsigned*)&lds[e + 4] = v.q.z;
        *(unsigned*)&lds[e + 6] = v.q.w;
      }
    }
    __syncthreads();

    #pragma unroll 1
    for (int b = 0; b < 2; ++b) {
      const int hh = ng * 2 + b;
      const int h  = c * 4 + hh;

      bf16x8 qa = (arow < NTOK)
          ? *(const bf16x8*)(qkv + (rowbase + arow) * 1152 + h * 32 + g * 8)
          : zbf8();

      f32x4 sv[4];
      #pragma unroll
      for (int nt = 0; nt < 4; ++nt) {
        int tok = nt * 16 + li;
        bf16x8 kf = (tok < NTOK)
            ? *(const bf16x8*)&lds[AT_K + tok * 128 + (((hh * 4 + g) ^ (tok & 7)) << 3)]
            : zbf8();
        f32x4 z4 = (f32x4){0.f, 0.f, 0.f, 0.f};
        sv[nt] = __builtin_amdgcn_mfma_f32_16x16x32_bf16(kf, qa, z4, 0, 0, 0);
      }

      const float* cb = cmb + (size_t)(wi * HEADS + h) * (NTOK * NTOK);
      #pragma unroll
      for (int nt = 0; nt < 4; ++nt) {
        #pragma unroll
        for (int r4 = 0; r4 < 4; ++r4) {
          int tok = nt * 16 + g * 4 + r4;
          float v;
          if (tok < NTOK) {
            v = sv[nt][r4];
            if (arow < NTOK) v += cb[tok * NTOK + arow];
          } else {
            v = -1e30f;
          }
          sv[nt][r4] = v;
        }
      }

      float m = -1e30f;
      #pragma unroll
      for (int nt = 0; nt < 4; ++nt)
        #pragma unroll
        for (int r4 = 0; r4 < 4; ++r4) m = fmaxf(m, sv[nt][r4]);
      m = fmaxf(m, __shfl_xor(m, 16));
      m = fmaxf(m, __shfl_xor(m, 32));
      float s = 0.f;
      #pragma unroll
      for (int nt = 0; nt < 4; ++nt)
        #pragma unroll
        for (int r4 = 0; r4 < 4; ++r4) {
          float e = __expf(sv[nt][r4] - m);
          sv[nt][r4] = e;
          s += e;
        }
      s += __shfl_xor(s, 16);
      s += __shfl_xor(s, 32);
      float inv = 1.f / s;
      #pragma unroll
      for (int nt = 0; nt < 4; ++nt)
        #pragma unroll
        for (int r4 = 0; r4 < 4; ++r4) sv[nt][r4] *= inv;

      bf16x8 pa[2];
      #pragma unroll
      for (int k2 = 0; k2 < 2; ++k2) {
        BF8 pf;
        #pragma unroll
        for (int j = 0; j < 8; ++j) {
          int srcLane = (((g * 2 + (j >> 2)) & 3) << 4) | li;
          float v0 = __shfl(sv[k2 * 2][j & 3], srcLane);
          float v1 = __shfl(sv[k2 * 2 + 1][j & 3], srcLane);
          pf.u[j] = f2bf((g >= 2) ? v1 : v0);
        }
        pa[k2] = pf.v;
      }

      f32x4 oa[2];
      oa[0] = (f32x4){0.f, 0.f, 0.f, 0.f};
      oa[1] = (f32x4){0.f, 0.f, 0.f, 0.f};
      #pragma unroll
      for (int k2 = 0; k2 < 2; ++k2) {
        #pragma unroll
        for (int nt2 = 0; nt2 < 2; ++nt2) {
          BF8 vb;
          int ch = hh * 32 + nt2 * 16 + li;
          #pragma unroll
          for (int j = 0; j < 8; ++j) {
            int tok = k2 * 32 + g * 8 + j;
            vb.u[j] = (tok < NTOK) ? lds[AT_V + tok * 138 + ch] : (unsigned short)0;
          }
          oa[nt2] = __builtin_amdgcn_mfma_f32_16x16x32_bf16(pa[k2], vb.v, oa[nt2], 0, 0, 0);
        }
      }

      // O -> swizzled image, key (grow>>1)&3 on granule low-2 bits
      #pragma unroll
      for (int nt2 = 0; nt2 < 2; ++nt2) {
        int colb = h * 32 + nt2 * 16 + li;
        int gran = colb >> 3;
        #pragma unroll
        for (int r4 = 0; r4 < 4; ++r4) {
          int row = mgrp * 16 + g * 4 + r4;
          if (row < NTOK) {
            int grow = (int)(rowbase) + row;
            int pos = swz4(gran, grow);
            Obuf[(size_t)grow * 384 + (pos << 3) + (colb & 7)] = f2bf(oa[nt2][r4]);
          }
        }
      }
    }
  }
}

extern "C" void kernel_launch(void* const* d_in, const int* in_sizes, int n_in,
                              void* d_out, int out_size, void* d_ws, size_t ws_size,
                              hipStream_t stream) {
  (void)in_sizes; (void)n_in; (void)out_size;
  const float* x          = (const float*)d_in[0];
  const float* mask       = (const float*)d_in[1];
  const float* qkv_w      = (const float*)d_in[2];
  const float* qkv_b      = (const float*)d_in[3];
  const float* proj_w     = (const float*)d_in[4];
  const float* proj_b     = (const float*)d_in[5];
  const float* bias_table = (const float*)d_in[6];
  const int*   rel_idx    = (const int*)d_in[7];
  float* out = (float*)d_out;

  char* ws = (char*)d_ws;
  size_t off = 0;
  unsigned short* wq  = (unsigned short*)(ws + off); off += (size_t)QKV_ELEMS * 2;
  unsigned short* wp  = (unsigned short*)(ws + off); off += (size_t)PROJ_ELEMS * 2;
  float*          qb2 = (float*)(ws + off);          off += (size_t)QKV_OC * 4;
  float*          cmb = (float*)(ws + off);          off += (size_t)CMB_ELEMS * 4;
  const size_t fixed = off;

  const int cands[7] = {4096, 2048, 1024, 512, 256, 128, 64};
  int WB = 64;
  for (int ci = 0; ci < 7; ++ci) {
    int mrows = cands[ci] * 49;
    int mpad = ((mrows + 127) / 128) * 128;
    size_t need = fixed + (size_t)mpad * 384 * 2 + (size_t)mrows * 1152 * 2;
    if (need <= ws_size) { WB = cands[ci]; break; }
  }
  const int Mrows = WB * 49;
  const int Mpad  = ((Mrows + 127) / 128) * 128;
  const int NRB   = Mpad / 128;
  unsigned short* xsw = (unsigned short*)(ws + fixed);   // x image / O image
  unsigned short* qkv = xsw + (size_t)Mpad * 384;

  const int prep_total = QKV_ELEMS + PROJ_ELEMS + CMB_ELEMS + QKV_OC;
  prep_kernel<<<(prep_total + 255) / 256, 256, 0, stream>>>(
      qkv_w, proj_w, bias_table, rel_idx, mask, qkv_b, wq, wp, cmb, qb2);

  const int NB = 4096 / WB;
  const long ngran = (long)Mrows * 48;
  for (int b = 0; b < NB; ++b) {
    convx_kernel<<<(int)((ngran + 255) / 256), 256, 0, stream>>>(
        x + (size_t)b * Mrows * 384, xsw, ngran);
    gemm128<1><<<NRB * 9, 256, 0, stream>>>(xsw, wq, qb2, (void*)qkv,
                                            Mrows, 1152, 9);
    attn_kernel<<<WB, 512, 0, stream>>>(qkv, cmb, xsw, b * WB);
    gemm128<0><<<NRB * 3, 256, 0, stream>>>(xsw, wp, proj_b,
        (void*)(out + (size_t)b * Mrows * 384), Mrows, 384, 3);
  }
}